// Round 1
// baseline (877.575 us; speedup 1.0000x reference)
//
#include <hip/hip_runtime.h>

// ---------------- preprocessing kernels ----------------

__global__ __launch_bounds__(256) void init_kernel(float* __restrict__ deg,
                                                   int* __restrict__ count, int n) {
    int i = blockIdx.x * 256 + threadIdx.x;
    if (i < n) { deg[i] = 1.0f; count[i] = 0; }   // self-loop weight 1
}

__global__ __launch_bounds__(256) void deg_hist_kernel(const int* __restrict__ src,
                                                       const int* __restrict__ dst,
                                                       const float* __restrict__ ew,
                                                       float* __restrict__ deg,
                                                       int* __restrict__ count, int E) {
    int e = blockIdx.x * 256 + threadIdx.x;
    if (e < E) {
        int d = dst[e];
        atomicAdd(&deg[d], ew[e]);
        atomicAdd(&count[d], 1);
    }
}

__global__ __launch_bounds__(256) void dinv_kernel(const float* __restrict__ deg,
                                                   float* __restrict__ dinv, int n) {
    int i = blockIdx.x * 256 + threadIdx.x;
    if (i < n) dinv[i] = rsqrtf(deg[i]);   // deg >= 1 always (self loop)
}

// single-block chunked exclusive scan: count[0..n) -> rowptr[0..n], cursor copy
__global__ __launch_bounds__(1024) void scan_kernel(const int* __restrict__ count,
                                                    int* __restrict__ rowptr,
                                                    int* __restrict__ cursor, int n) {
    __shared__ int sums[1024];
    int t = threadIdx.x;
    int ch = (n + 1023) / 1024;
    int beg = t * ch;
    int end = min(beg + ch, n);
    int s = 0;
    for (int i = beg; i < end; ++i) s += count[i];
    sums[t] = s;
    __syncthreads();
    // Hillis-Steele inclusive scan over 1024 partials
    for (int off = 1; off < 1024; off <<= 1) {
        int add = (t >= off) ? sums[t - off] : 0;
        __syncthreads();
        sums[t] += add;
        __syncthreads();
    }
    int run = (t == 0) ? 0 : sums[t - 1];
    for (int i = beg; i < end; ++i) {
        rowptr[i] = run;
        cursor[i] = run;
        run += count[i];
    }
    if (t == 1023) rowptr[n] = sums[1023];
}

__global__ __launch_bounds__(256) void scatter_kernel(const int* __restrict__ src,
                                                      const int* __restrict__ dst,
                                                      const float* __restrict__ ew,
                                                      const float* __restrict__ dinv,
                                                      int* __restrict__ cursor,
                                                      int* __restrict__ srcs,
                                                      float* __restrict__ norms, int E) {
    int e = blockIdx.x * 256 + threadIdx.x;
    if (e < E) {
        int s = src[e], d = dst[e];
        float w = dinv[s] * ew[e] * dinv[d];
        int pos = atomicAdd(&cursor[d], 1);
        srcs[pos] = s;
        norms[pos] = w;
    }
}

// ---------------- dense GEMM: Y[nrows,128] = X[nrows,128] @ W[128,128] ----------------
// block = 256 threads, tile = 64 rows x 128 cols, K blocked by 32.
__global__ __launch_bounds__(256) void gemm128(const float* __restrict__ X,
                                               const float* __restrict__ W,
                                               float* __restrict__ Y, int nrows) {
    __shared__ float As[64 * 33];    // [row][k], pad 33 to dodge bank conflicts
    __shared__ float Ws[32 * 132];   // [k][col], pad 132 (multiple of 4 for float4)

    int t  = threadIdx.x;
    int ty = t >> 4;        // 0..15 -> row group (4 rows)
    int tx = t & 15;        // 0..15 -> col group (8 cols)
    int r0 = blockIdx.x * 64;

    float acc[4][8];
#pragma unroll
    for (int i = 0; i < 4; ++i)
#pragma unroll
        for (int j = 0; j < 8; ++j) acc[i][j] = 0.0f;

    for (int kb = 0; kb < 4; ++kb) {
        // stage A tile: lanes vary k (coalesced), 8 rows per thread
        {
            int k = t & 31;
            int rbase = (t >> 5) * 8;
#pragma unroll
            for (int j = 0; j < 8; ++j) {
                int r = rbase + j;
                int gr = r0 + r;
                float v = 0.0f;
                if (gr < nrows) v = X[(size_t)gr * 128 + kb * 32 + k];
                As[r * 33 + k] = v;
            }
        }
        // stage W tile: row = t>>3 (0..31), 16 cols per thread (4 float4)
        {
            int wr = t >> 3;
            int wc = (t & 7) * 16;
            const float4* Wg = (const float4*)(W + (size_t)(kb * 32 + wr) * 128 + wc);
            float4* Wl = (float4*)(Ws + wr * 132 + wc);
#pragma unroll
            for (int j = 0; j < 4; ++j) Wl[j] = Wg[j];
        }
        __syncthreads();

#pragma unroll 8
        for (int k = 0; k < 32; ++k) {
            float a[4];
#pragma unroll
            for (int i = 0; i < 4; ++i) a[i] = As[(ty * 4 + i) * 33 + k];
            float4 b0 = *(const float4*)(Ws + k * 132 + tx * 8);
            float4 b1 = *(const float4*)(Ws + k * 132 + tx * 8 + 4);
#pragma unroll
            for (int i = 0; i < 4; ++i) {
                acc[i][0] += a[i] * b0.x;
                acc[i][1] += a[i] * b0.y;
                acc[i][2] += a[i] * b0.z;
                acc[i][3] += a[i] * b0.w;
                acc[i][4] += a[i] * b1.x;
                acc[i][5] += a[i] * b1.y;
                acc[i][6] += a[i] * b1.z;
                acc[i][7] += a[i] * b1.w;
            }
        }
        __syncthreads();
    }

#pragma unroll
    for (int i = 0; i < 4; ++i) {
        int gr = r0 + ty * 4 + i;
        if (gr < nrows) {
            float4 o0 = {acc[i][0], acc[i][1], acc[i][2], acc[i][3]};
            float4 o1 = {acc[i][4], acc[i][5], acc[i][6], acc[i][7]};
            *(float4*)(Y + (size_t)gr * 128 + tx * 8) = o0;
            *(float4*)(Y + (size_t)gr * 128 + tx * 8 + 4) = o1;
        }
    }
}

// ---------------- aggregation: out[n] = relu(sum_{e in CSR[n]} norm_e * F[src_e] + dinv[n]^2 * F[n] + b) ----------------
// one wave per node, lane handles feature cols 2*lane, 2*lane+1
__global__ __launch_bounds__(256) void agg_kernel(const float* __restrict__ F,
                                                  const int* __restrict__ rowptr,
                                                  const int* __restrict__ srcs,
                                                  const float* __restrict__ norms,
                                                  const float* __restrict__ dinv,
                                                  const float* __restrict__ bias,
                                                  float* __restrict__ out, int n) {
    int wid  = (blockIdx.x * 256 + threadIdx.x) >> 6;
    int lane = threadIdx.x & 63;
    int node = __builtin_amdgcn_readfirstlane(wid);
    if (node >= n) return;

    int beg = rowptr[node];
    int end = rowptr[node + 1];
    float di = dinv[node];
    float selfw = di * di;

    float2 fs = *(const float2*)(F + (size_t)node * 128 + 2 * lane);
    float accx = selfw * fs.x;
    float accy = selfw * fs.y;

    int e = beg;
    for (; e + 4 <= end; e += 4) {
        int s0 = srcs[e + 0], s1 = srcs[e + 1], s2 = srcs[e + 2], s3 = srcs[e + 3];
        float w0 = norms[e + 0], w1 = norms[e + 1], w2 = norms[e + 2], w3 = norms[e + 3];
        float2 f0 = *(const float2*)(F + (size_t)s0 * 128 + 2 * lane);
        float2 f1 = *(const float2*)(F + (size_t)s1 * 128 + 2 * lane);
        float2 f2 = *(const float2*)(F + (size_t)s2 * 128 + 2 * lane);
        float2 f3 = *(const float2*)(F + (size_t)s3 * 128 + 2 * lane);
        accx += w0 * f0.x; accy += w0 * f0.y;
        accx += w1 * f1.x; accy += w1 * f1.y;
        accx += w2 * f2.x; accy += w2 * f2.y;
        accx += w3 * f3.x; accy += w3 * f3.y;
    }
    for (; e < end; ++e) {
        int s = srcs[e];
        float w = norms[e];
        float2 fv = *(const float2*)(F + (size_t)s * 128 + 2 * lane);
        accx += w * fv.x; accy += w * fv.y;
    }

    float2 bv = *(const float2*)(bias + 2 * lane);
    accx = fmaxf(accx + bv.x, 0.0f);
    accy = fmaxf(accy + bv.y, 0.0f);
    *(float2*)(out + (size_t)node * 128 + 2 * lane) = make_float2(accx, accy);
}

// ---------------- launcher ----------------

extern "C" void kernel_launch(void* const* d_in, const int* in_sizes, int n_in,
                              void* d_out, int out_size, void* d_ws, size_t ws_size,
                              hipStream_t stream) {
    const float* x  = (const float*)d_in[0];
    const int*   ei = (const int*)d_in[1];
    const float* ew = (const float*)d_in[2];
    const float* W1 = (const float*)d_in[3];
    const float* b1 = (const float*)d_in[4];
    const float* W2 = (const float*)d_in[5];
    const float* b2 = (const float*)d_in[6];
    float* out = (float*)d_out;

    const int N = in_sizes[0] / 128;
    const int E = in_sizes[2];
    const int* src = ei;
    const int* dst = ei + E;

    // workspace layout (all 4-byte elems; bufA at offset 0 keeps 16B alignment)
    float* bufA   = (float*)d_ws;                 // N*128 floats
    float* norms  = bufA + (size_t)N * 128;       // E
    float* deg    = norms + E;                    // N
    float* dinv   = deg + N;                      // N
    int*   srcs   = (int*)(dinv + N);             // E
    int*   count  = srcs + E;                     // N
    int*   rowptr = count + N;                    // N+1
    int*   cursor = rowptr + N + 1;               // N

    const int nb_n = (N + 255) / 256;
    const int nb_e = (E + 255) / 256;

    hipLaunchKernelGGL(init_kernel, dim3(nb_n), dim3(256), 0, stream, deg, count, N);
    hipLaunchKernelGGL(deg_hist_kernel, dim3(nb_e), dim3(256), 0, stream, src, dst, ew, deg, count, E);
    hipLaunchKernelGGL(dinv_kernel, dim3(nb_n), dim3(256), 0, stream, deg, dinv, N);
    hipLaunchKernelGGL(scan_kernel, dim3(1), dim3(1024), 0, stream, count, rowptr, cursor, N);
    hipLaunchKernelGGL(scatter_kernel, dim3(nb_e), dim3(256), 0, stream, src, dst, ew, dinv, cursor, srcs, norms, E);

    // layer 1: xw = x@W1 -> bufA ; h = relu(agg(bufA)+b1) -> d_out
    hipLaunchKernelGGL(gemm128, dim3((N + 63) / 64), dim3(256), 0, stream, x, W1, bufA, N);
    hipLaunchKernelGGL(agg_kernel, dim3((N + 3) / 4), dim3(256), 0, stream, bufA, rowptr, srcs, norms, dinv, b1, out, N);

    // layer 2: hw = h@W2 -> bufA ; out = relu(agg(bufA)+b2) -> d_out
    hipLaunchKernelGGL(gemm128, dim3((N + 63) / 64), dim3(256), 0, stream, out, W2, bufA, N);
    hipLaunchKernelGGL(agg_kernel, dim3((N + 3) / 4), dim3(256), 0, stream, bufA, rowptr, srcs, norms, dinv, b2, out, N);
}

// Round 2
// 652.397 us; speedup vs baseline: 1.3452x; 1.3452x over previous
//
#include <hip/hip_runtime.h>

// ---------------- preprocessing kernels ----------------

__global__ __launch_bounds__(256) void init_kernel(float* __restrict__ deg,
                                                   int* __restrict__ count, int n) {
    int i = blockIdx.x * 256 + threadIdx.x;
    if (i < n) { deg[i] = 1.0f; count[i] = 0; }   // self-loop weight 1
}

__global__ __launch_bounds__(256) void deg_hist_kernel(const int* __restrict__ src,
                                                       const int* __restrict__ dst,
                                                       const float* __restrict__ ew,
                                                       float* __restrict__ deg,
                                                       int* __restrict__ count, int E) {
    int e = blockIdx.x * 256 + threadIdx.x;
    if (e < E) {
        int d = dst[e];
        atomicAdd(&deg[d], ew[e]);
        atomicAdd(&count[d], 1);
    }
}

__global__ __launch_bounds__(256) void dinv_kernel(const float* __restrict__ deg,
                                                   float* __restrict__ dinv, int n) {
    int i = blockIdx.x * 256 + threadIdx.x;
    if (i < n) dinv[i] = rsqrtf(deg[i]);   // deg >= 1 always (self loop)
}

// ---------------- device-wide exclusive scan: count -> rowptr ----------------
// Phase A: each block scans a 1024-elem tile (256 thr x 4), local-exclusive into
//          rowptr, tile total into blocksums[blockIdx.x].
#define SCAN_TILE 1024

__global__ __launch_bounds__(256) void scanA_kernel(const int* __restrict__ count,
                                                    int* __restrict__ rowptr,
                                                    int* __restrict__ blocksums, int n) {
    __shared__ int sums[256];
    int t = threadIdx.x;
    int base = blockIdx.x * SCAN_TILE + t * 4;
    int v0 = (base + 0 < n) ? count[base + 0] : 0;
    int v1 = (base + 1 < n) ? count[base + 1] : 0;
    int v2 = (base + 2 < n) ? count[base + 2] : 0;
    int v3 = (base + 3 < n) ? count[base + 3] : 0;
    sums[t] = v0 + v1 + v2 + v3;
    __syncthreads();
    for (int off = 1; off < 256; off <<= 1) {
        int add = (t >= off) ? sums[t - off] : 0;
        __syncthreads();
        sums[t] += add;
        __syncthreads();
    }
    int run = (t == 0) ? 0 : sums[t - 1];
    if (base + 0 < n) rowptr[base + 0] = run; run += v0;
    if (base + 1 < n) rowptr[base + 1] = run; run += v1;
    if (base + 2 < n) rowptr[base + 2] = run; run += v2;
    if (base + 3 < n) rowptr[base + 3] = run;
    if (t == 255) blocksums[blockIdx.x] = sums[255];
}

// Phase B: exclusive-scan blocksums in place (nb <= 256)
__global__ __launch_bounds__(256) void scanB_kernel(int* __restrict__ blocksums, int nb) {
    __shared__ int sums[256];
    int t = threadIdx.x;
    sums[t] = (t < nb) ? blocksums[t] : 0;
    __syncthreads();
    for (int off = 1; off < 256; off <<= 1) {
        int add = (t >= off) ? sums[t - off] : 0;
        __syncthreads();
        sums[t] += add;
        __syncthreads();
    }
    if (t < nb) blocksums[t] = (t == 0) ? 0 : sums[t - 1];
}

// Phase C: add tile offsets in place, copy to cursor, set rowptr[n]=E
__global__ __launch_bounds__(256) void scanC_kernel(int* __restrict__ rowptr,
                                                    const int* __restrict__ blocksums,
                                                    int* __restrict__ cursor, int n, int E) {
    int i = blockIdx.x * 256 + threadIdx.x;
    if (i < n) {
        int v = rowptr[i] + blocksums[i / SCAN_TILE];
        rowptr[i] = v;
        cursor[i] = v;
    }
    if (i == 0) rowptr[n] = E;
}

__global__ __launch_bounds__(256) void scatter_kernel(const int* __restrict__ src,
                                                      const int* __restrict__ dst,
                                                      const float* __restrict__ ew,
                                                      const float* __restrict__ dinv,
                                                      int* __restrict__ cursor,
                                                      int* __restrict__ srcs,
                                                      float* __restrict__ norms, int E) {
    int e = blockIdx.x * 256 + threadIdx.x;
    if (e < E) {
        int s = src[e], d = dst[e];
        float w = dinv[s] * ew[e] * dinv[d];
        int pos = atomicAdd(&cursor[d], 1);
        srcs[pos] = s;
        norms[pos] = w;
    }
}

// ---------------- dense GEMM: Y[nrows,128] = X[nrows,128] @ W[128,128] ----------------
// block = 256 threads, tile = 64 rows x 128 cols, K blocked by 32.
__global__ __launch_bounds__(256) void gemm128(const float* __restrict__ X,
                                               const float* __restrict__ W,
                                               float* __restrict__ Y, int nrows) {
    __shared__ float As[64 * 33];    // [row][k], pad 33 to dodge bank conflicts
    __shared__ float Ws[32 * 132];   // [k][col], pad 132 (multiple of 4 for float4)

    int t  = threadIdx.x;
    int ty = t >> 4;        // 0..15 -> row group (4 rows)
    int tx = t & 15;        // 0..15 -> col group (8 cols)
    int r0 = blockIdx.x * 64;

    float acc[4][8];
#pragma unroll
    for (int i = 0; i < 4; ++i)
#pragma unroll
        for (int j = 0; j < 8; ++j) acc[i][j] = 0.0f;

    for (int kb = 0; kb < 4; ++kb) {
        // stage A tile: lanes vary k (coalesced), 8 rows per thread
        {
            int k = t & 31;
            int rbase = (t >> 5) * 8;
#pragma unroll
            for (int j = 0; j < 8; ++j) {
                int r = rbase + j;
                int gr = r0 + r;
                float v = 0.0f;
                if (gr < nrows) v = X[(size_t)gr * 128 + kb * 32 + k];
                As[r * 33 + k] = v;
            }
        }
        // stage W tile: row = t>>3 (0..31), 16 cols per thread (4 float4)
        {
            int wr = t >> 3;
            int wc = (t & 7) * 16;
            const float4* Wg = (const float4*)(W + (size_t)(kb * 32 + wr) * 128 + wc);
            float4* Wl = (float4*)(Ws + wr * 132 + wc);
#pragma unroll
            for (int j = 0; j < 4; ++j) Wl[j] = Wg[j];
        }
        __syncthreads();

#pragma unroll 8
        for (int k = 0; k < 32; ++k) {
            float a[4];
#pragma unroll
            for (int i = 0; i < 4; ++i) a[i] = As[(ty * 4 + i) * 33 + k];
            float4 b0 = *(const float4*)(Ws + k * 132 + tx * 8);
            float4 b1 = *(const float4*)(Ws + k * 132 + tx * 8 + 4);
#pragma unroll
            for (int i = 0; i < 4; ++i) {
                acc[i][0] += a[i] * b0.x;
                acc[i][1] += a[i] * b0.y;
                acc[i][2] += a[i] * b0.z;
                acc[i][3] += a[i] * b0.w;
                acc[i][4] += a[i] * b1.x;
                acc[i][5] += a[i] * b1.y;
                acc[i][6] += a[i] * b1.z;
                acc[i][7] += a[i] * b1.w;
            }
        }
        __syncthreads();
    }

#pragma unroll
    for (int i = 0; i < 4; ++i) {
        int gr = r0 + ty * 4 + i;
        if (gr < nrows) {
            float4 o0 = {acc[i][0], acc[i][1], acc[i][2], acc[i][3]};
            float4 o1 = {acc[i][4], acc[i][5], acc[i][6], acc[i][7]};
            *(float4*)(Y + (size_t)gr * 128 + tx * 8) = o0;
            *(float4*)(Y + (size_t)gr * 128 + tx * 8 + 4) = o1;
        }
    }
}

// ---------------- aggregation: out[n] = relu(sum_{e in CSR[n]} norm_e * F[src_e] + dinv[n]^2 * F[n] + b) ----------------
// one wave per node, lane handles feature cols 2*lane, 2*lane+1
__global__ __launch_bounds__(256) void agg_kernel(const float* __restrict__ F,
                                                  const int* __restrict__ rowptr,
                                                  const int* __restrict__ srcs,
                                                  const float* __restrict__ norms,
                                                  const float* __restrict__ dinv,
                                                  const float* __restrict__ bias,
                                                  float* __restrict__ out, int n) {
    int wid  = (blockIdx.x * 256 + threadIdx.x) >> 6;
    int lane = threadIdx.x & 63;
    int node = __builtin_amdgcn_readfirstlane(wid);
    if (node >= n) return;

    int beg = rowptr[node];
    int end = rowptr[node + 1];
    float di = dinv[node];
    float selfw = di * di;

    float2 fs = *(const float2*)(F + (size_t)node * 128 + 2 * lane);
    float accx = selfw * fs.x;
    float accy = selfw * fs.y;

    int e = beg;
    for (; e + 4 <= end; e += 4) {
        int s0 = srcs[e + 0], s1 = srcs[e + 1], s2 = srcs[e + 2], s3 = srcs[e + 3];
        float w0 = norms[e + 0], w1 = norms[e + 1], w2 = norms[e + 2], w3 = norms[e + 3];
        float2 f0 = *(const float2*)(F + (size_t)s0 * 128 + 2 * lane);
        float2 f1 = *(const float2*)(F + (size_t)s1 * 128 + 2 * lane);
        float2 f2 = *(const float2*)(F + (size_t)s2 * 128 + 2 * lane);
        float2 f3 = *(const float2*)(F + (size_t)s3 * 128 + 2 * lane);
        accx += w0 * f0.x; accy += w0 * f0.y;
        accx += w1 * f1.x; accy += w1 * f1.y;
        accx += w2 * f2.x; accy += w2 * f2.y;
        accx += w3 * f3.x; accy += w3 * f3.y;
    }
    for (; e < end; ++e) {
        int s = srcs[e];
        float w = norms[e];
        float2 fv = *(const float2*)(F + (size_t)s * 128 + 2 * lane);
        accx += w * fv.x; accy += w * fv.y;
    }

    float2 bv = *(const float2*)(bias + 2 * lane);
    accx = fmaxf(accx + bv.x, 0.0f);
    accy = fmaxf(accy + bv.y, 0.0f);
    *(float2*)(out + (size_t)node * 128 + 2 * lane) = make_float2(accx, accy);
}

// ---------------- launcher ----------------

extern "C" void kernel_launch(void* const* d_in, const int* in_sizes, int n_in,
                              void* d_out, int out_size, void* d_ws, size_t ws_size,
                              hipStream_t stream) {
    const float* x  = (const float*)d_in[0];
    const int*   ei = (const int*)d_in[1];
    const float* ew = (const float*)d_in[2];
    const float* W1 = (const float*)d_in[3];
    const float* b1 = (const float*)d_in[4];
    const float* W2 = (const float*)d_in[5];
    const float* b2 = (const float*)d_in[6];
    float* out = (float*)d_out;

    const int N = in_sizes[0] / 128;
    const int E = in_sizes[2];
    const int* src = ei;
    const int* dst = ei + E;

    // workspace layout (all 4-byte elems; bufA at offset 0 keeps 16B alignment)
    float* bufA   = (float*)d_ws;                 // N*128 floats
    float* norms  = bufA + (size_t)N * 128;       // E
    float* deg    = norms + E;                    // N
    float* dinv   = deg + N;                      // N
    int*   srcs   = (int*)(dinv + N);             // E
    int*   count  = srcs + E;                     // N
    int*   rowptr = count + N;                    // N+1
    int*   cursor = rowptr + N + 1;               // N
    int*   bsums  = cursor + N;                   // ceil(N/1024)

    const int nb_n = (N + 255) / 256;
    const int nb_e = (E + 255) / 256;
    const int nb_s = (N + SCAN_TILE - 1) / SCAN_TILE;   // scan tiles (<=256)

    hipLaunchKernelGGL(init_kernel, dim3(nb_n), dim3(256), 0, stream, deg, count, N);
    hipLaunchKernelGGL(deg_hist_kernel, dim3(nb_e), dim3(256), 0, stream, src, dst, ew, deg, count, E);
    hipLaunchKernelGGL(dinv_kernel, dim3(nb_n), dim3(256), 0, stream, deg, dinv, N);
    hipLaunchKernelGGL(scanA_kernel, dim3(nb_s), dim3(256), 0, stream, count, rowptr, bsums, N);
    hipLaunchKernelGGL(scanB_kernel, dim3(1), dim3(256), 0, stream, bsums, nb_s);
    hipLaunchKernelGGL(scanC_kernel, dim3(nb_n), dim3(256), 0, stream, rowptr, bsums, cursor, N, E);
    hipLaunchKernelGGL(scatter_kernel, dim3(nb_e), dim3(256), 0, stream, src, dst, ew, dinv, cursor, srcs, norms, E);

    // layer 1: xw = x@W1 -> bufA ; h = relu(agg(bufA)+b1) -> d_out
    hipLaunchKernelGGL(gemm128, dim3((N + 63) / 64), dim3(256), 0, stream, x, W1, bufA, N);
    hipLaunchKernelGGL(agg_kernel, dim3((N + 3) / 4), dim3(256), 0, stream, bufA, rowptr, srcs, norms, dinv, b1, out, N);

    // layer 2: hw = h@W2 -> bufA ; out = relu(agg(bufA)+b2) -> d_out
    hipLaunchKernelGGL(gemm128, dim3((N + 63) / 64), dim3(256), 0, stream, out, W2, bufA, N);
    hipLaunchKernelGGL(agg_kernel, dim3((N + 3) / 4), dim3(256), 0, stream, bufA, rowptr, srcs, norms, dinv, b2, out, N);
}

// Round 3
// 473.628 us; speedup vs baseline: 1.8529x; 1.3774x over previous
//
#include <hip/hip_runtime.h>

#define NPB 256        // nodes per bucket (dst >> 8)
#define PBLK 256       // partition blocks

// ---------------- phase 1: per-(block,bucket) histogram ----------------
__global__ __launch_bounds__(256) void p1_hist(const int* __restrict__ dst,
                                               int* __restrict__ MT, int E, int NB, int chunk) {
    __shared__ int h[512];
    int t = threadIdx.x, p = blockIdx.x;
    for (int i = t; i < NB; i += 256) h[i] = 0;
    __syncthreads();
    int beg = p * chunk, end = min(beg + chunk, E);
    for (int e = beg + t; e < end; e += 256) atomicAdd(&h[dst[e] >> 8], 1);
    __syncthreads();
    for (int b = t; b < NB; b += 256) MT[b * PBLK + p] = h[b];
}

// ---------------- device-wide exclusive scan (1024-elem tiles) ----------------
#define SCAN_TILE 1024

__global__ __launch_bounds__(256) void scanA_kernel(const int* __restrict__ in,
                                                    int* __restrict__ out,
                                                    int* __restrict__ blocksums, int n) {
    __shared__ int sums[256];
    int t = threadIdx.x;
    int base = blockIdx.x * SCAN_TILE + t * 4;
    int v0 = (base + 0 < n) ? in[base + 0] : 0;
    int v1 = (base + 1 < n) ? in[base + 1] : 0;
    int v2 = (base + 2 < n) ? in[base + 2] : 0;
    int v3 = (base + 3 < n) ? in[base + 3] : 0;
    sums[t] = v0 + v1 + v2 + v3;
    __syncthreads();
    for (int off = 1; off < 256; off <<= 1) {
        int add = (t >= off) ? sums[t - off] : 0;
        __syncthreads();
        sums[t] += add;
        __syncthreads();
    }
    int run = (t == 0) ? 0 : sums[t - 1];
    if (base + 0 < n) out[base + 0] = run; run += v0;
    if (base + 1 < n) out[base + 1] = run; run += v1;
    if (base + 2 < n) out[base + 2] = run; run += v2;
    if (base + 3 < n) out[base + 3] = run;
    if (t == 255) blocksums[blockIdx.x] = sums[255];
}

__global__ __launch_bounds__(256) void scanB_kernel(int* __restrict__ blocksums, int nb) {
    __shared__ int sums[256];
    int t = threadIdx.x;
    sums[t] = (t < nb) ? blocksums[t] : 0;
    __syncthreads();
    for (int off = 1; off < 256; off <<= 1) {
        int add = (t >= off) ? sums[t - off] : 0;
        __syncthreads();
        sums[t] += add;
        __syncthreads();
    }
    if (t < nb) blocksums[t] = (t == 0) ? 0 : sums[t - 1];
}

__global__ __launch_bounds__(256) void scanC_kernel(int* __restrict__ data,
                                                    const int* __restrict__ blocksums, int n) {
    int i = blockIdx.x * 256 + threadIdx.x;
    if (i < n) data[i] += blocksums[i / SCAN_TILE];
}

// ---------------- phase 2: partition edges into buckets (LDS cursors only) ----------------
__global__ __launch_bounds__(256) void p2_part(const int* __restrict__ src,
                                               const int* __restrict__ dst,
                                               const float* __restrict__ ew,
                                               const int* __restrict__ MTs,
                                               int* __restrict__ pp, float* __restrict__ pw,
                                               int E, int NB, int chunk) {
    __shared__ int cur[512];
    int t = threadIdx.x, p = blockIdx.x;
    for (int b = t; b < NB; b += 256) cur[b] = MTs[b * PBLK + p];
    __syncthreads();
    int beg = p * chunk, end = min(beg + chunk, E);
    for (int e = beg + t; e < end; e += 256) {
        int d = dst[e];
        int b = d >> 8;
        int pos = atomicAdd(&cur[b], 1);
        pp[pos] = src[e] | ((d & 255) << 20);   // src < 2^20, dlocal in [0,256)
        pw[pos] = ew[e];
    }
}

// ---------------- phase 3: per-bucket exact CSR + degree + dinv ----------------
__global__ __launch_bounds__(256) void p3_bucket(const int* __restrict__ pp,
                                                 const float* __restrict__ pw,
                                                 const int* __restrict__ MTs,
                                                 int* __restrict__ srcs,
                                                 float* __restrict__ norms_ew,
                                                 int* __restrict__ rowptr,
                                                 float* __restrict__ dinv,
                                                 int E, int N, int NB) {
    __shared__ int cnt[256];
    __shared__ float wd[256];
    __shared__ int ls[256];
    __shared__ int cur[256];
    int t = threadIdx.x, b = blockIdx.x;
    int beg = MTs[b * PBLK];
    int end = (b == NB - 1) ? E : MTs[(b + 1) * PBLK];
    cnt[t] = 0;
    wd[t] = 0.0f;
    __syncthreads();
    for (int e = beg + t; e < end; e += 256) {
        int v = pp[e];
        int dl = v >> 20;
        atomicAdd(&cnt[dl], 1);
        atomicAdd(&wd[dl], pw[e]);
    }
    __syncthreads();
    ls[t] = cnt[t];
    __syncthreads();
    for (int off = 1; off < 256; off <<= 1) {
        int add = (t >= off) ? ls[t - off] : 0;
        __syncthreads();
        ls[t] += add;
        __syncthreads();
    }
    int excl = (t == 0) ? 0 : ls[t - 1];
    int node = b * NPB + t;
    if (node < N) {
        rowptr[node] = beg + excl;
        dinv[node] = rsqrtf(1.0f + wd[t]);   // +1 = self-loop weight
    }
    cur[t] = beg + excl;
    if (b == NB - 1 && t == 0) rowptr[N] = E;
    __syncthreads();
    for (int e = beg + t; e < end; e += 256) {
        int v = pp[e];
        int dl = v >> 20;
        int pos = atomicAdd(&cur[dl], 1);
        srcs[pos] = v & 0xFFFFF;
        norms_ew[pos] = pw[e];   // raw ew for now; finalized below
    }
}

// ---------------- finalize: norms[p] = dinv[src] * ew * dinv[dst], in place ----------------
__global__ __launch_bounds__(256) void finalize_kernel(const int* __restrict__ rowptr,
                                                       const int* __restrict__ srcs,
                                                       const float* __restrict__ dinv,
                                                       float* __restrict__ norms, int n) {
    int wid  = (blockIdx.x * 256 + threadIdx.x) >> 6;
    int lane = threadIdx.x & 63;
    if (wid >= n) return;
    int beg = rowptr[wid];
    int end = rowptr[wid + 1];
    float di = dinv[wid];
    for (int p = beg + lane; p < end; p += 64) {
        norms[p] = dinv[srcs[p]] * norms[p] * di;
    }
}

// ---------------- dense GEMM: Y[nrows,128] = X[nrows,128] @ W[128,128] ----------------
__global__ __launch_bounds__(256) void gemm128(const float* __restrict__ X,
                                               const float* __restrict__ W,
                                               float* __restrict__ Y, int nrows) {
    __shared__ float As[64 * 33];
    __shared__ float Ws[32 * 132];

    int t  = threadIdx.x;
    int ty = t >> 4;
    int tx = t & 15;
    int r0 = blockIdx.x * 64;

    float acc[4][8];
#pragma unroll
    for (int i = 0; i < 4; ++i)
#pragma unroll
        for (int j = 0; j < 8; ++j) acc[i][j] = 0.0f;

    for (int kb = 0; kb < 4; ++kb) {
        {
            int k = t & 31;
            int rbase = (t >> 5) * 8;
#pragma unroll
            for (int j = 0; j < 8; ++j) {
                int r = rbase + j;
                int gr = r0 + r;
                float v = 0.0f;
                if (gr < nrows) v = X[(size_t)gr * 128 + kb * 32 + k];
                As[r * 33 + k] = v;
            }
        }
        {
            int wr = t >> 3;
            int wc = (t & 7) * 16;
            const float4* Wg = (const float4*)(W + (size_t)(kb * 32 + wr) * 128 + wc);
            float4* Wl = (float4*)(Ws + wr * 132 + wc);
#pragma unroll
            for (int j = 0; j < 4; ++j) Wl[j] = Wg[j];
        }
        __syncthreads();

#pragma unroll 8
        for (int k = 0; k < 32; ++k) {
            float a[4];
#pragma unroll
            for (int i = 0; i < 4; ++i) a[i] = As[(ty * 4 + i) * 33 + k];
            float4 b0 = *(const float4*)(Ws + k * 132 + tx * 8);
            float4 b1 = *(const float4*)(Ws + k * 132 + tx * 8 + 4);
#pragma unroll
            for (int i = 0; i < 4; ++i) {
                acc[i][0] += a[i] * b0.x;
                acc[i][1] += a[i] * b0.y;
                acc[i][2] += a[i] * b0.z;
                acc[i][3] += a[i] * b0.w;
                acc[i][4] += a[i] * b1.x;
                acc[i][5] += a[i] * b1.y;
                acc[i][6] += a[i] * b1.z;
                acc[i][7] += a[i] * b1.w;
            }
        }
        __syncthreads();
    }

#pragma unroll
    for (int i = 0; i < 4; ++i) {
        int gr = r0 + ty * 4 + i;
        if (gr < nrows) {
            float4 o0 = {acc[i][0], acc[i][1], acc[i][2], acc[i][3]};
            float4 o1 = {acc[i][4], acc[i][5], acc[i][6], acc[i][7]};
            *(float4*)(Y + (size_t)gr * 128 + tx * 8) = o0;
            *(float4*)(Y + (size_t)gr * 128 + tx * 8 + 4) = o1;
        }
    }
}

// ---------------- aggregation ----------------
__global__ __launch_bounds__(256) void agg_kernel(const float* __restrict__ F,
                                                  const int* __restrict__ rowptr,
                                                  const int* __restrict__ srcs,
                                                  const float* __restrict__ norms,
                                                  const float* __restrict__ dinv,
                                                  const float* __restrict__ bias,
                                                  float* __restrict__ out, int n) {
    int wid  = (blockIdx.x * 256 + threadIdx.x) >> 6;
    int lane = threadIdx.x & 63;
    int node = __builtin_amdgcn_readfirstlane(wid);
    if (node >= n) return;

    int beg = rowptr[node];
    int end = rowptr[node + 1];
    float di = dinv[node];
    float selfw = di * di;

    float2 fs = *(const float2*)(F + (size_t)node * 128 + 2 * lane);
    float accx = selfw * fs.x;
    float accy = selfw * fs.y;

    int e = beg;
    for (; e + 4 <= end; e += 4) {
        int s0 = srcs[e + 0], s1 = srcs[e + 1], s2 = srcs[e + 2], s3 = srcs[e + 3];
        float w0 = norms[e + 0], w1 = norms[e + 1], w2 = norms[e + 2], w3 = norms[e + 3];
        float2 f0 = *(const float2*)(F + (size_t)s0 * 128 + 2 * lane);
        float2 f1 = *(const float2*)(F + (size_t)s1 * 128 + 2 * lane);
        float2 f2 = *(const float2*)(F + (size_t)s2 * 128 + 2 * lane);
        float2 f3 = *(const float2*)(F + (size_t)s3 * 128 + 2 * lane);
        accx += w0 * f0.x; accy += w0 * f0.y;
        accx += w1 * f1.x; accy += w1 * f1.y;
        accx += w2 * f2.x; accy += w2 * f2.y;
        accx += w3 * f3.x; accy += w3 * f3.y;
    }
    for (; e < end; ++e) {
        int s = srcs[e];
        float w = norms[e];
        float2 fv = *(const float2*)(F + (size_t)s * 128 + 2 * lane);
        accx += w * fv.x; accy += w * fv.y;
    }

    float2 bv = *(const float2*)(bias + 2 * lane);
    accx = fmaxf(accx + bv.x, 0.0f);
    accy = fmaxf(accy + bv.y, 0.0f);
    *(float2*)(out + (size_t)node * 128 + 2 * lane) = make_float2(accx, accy);
}

// ---------------- launcher ----------------

extern "C" void kernel_launch(void* const* d_in, const int* in_sizes, int n_in,
                              void* d_out, int out_size, void* d_ws, size_t ws_size,
                              hipStream_t stream) {
    const float* x  = (const float*)d_in[0];
    const int*   ei = (const int*)d_in[1];
    const float* ew = (const float*)d_in[2];
    const float* W1 = (const float*)d_in[3];
    const float* b1 = (const float*)d_in[4];
    const float* W2 = (const float*)d_in[5];
    const float* b2 = (const float*)d_in[6];
    float* out = (float*)d_out;

    const int N = in_sizes[0] / 128;
    const int E = in_sizes[2];
    const int* src = ei;
    const int* dst = ei + E;

    const int NB = (N + NPB - 1) / NPB;        // buckets (391 for N=100k)
    const int L  = NB * PBLK;                  // count-matrix length
    const int chunk = (E + PBLK - 1) / PBLK;

    // workspace layout. pp/pw alias the front of bufA (dead before GEMM writes it).
    float* bufA   = (float*)d_ws;              // N*128 floats
    int*   pp     = (int*)d_ws;                // E ints   (alias)
    float* pw     = (float*)(pp + E);          // E floats (alias)
    int*   srcs   = (int*)(bufA + (size_t)N * 128);  // E
    float* norms  = (float*)(srcs + E);        // E
    int*   rowptr = (int*)(norms + E);         // N+1
    float* dinv   = (float*)(rowptr + N + 1);  // N
    int*   MT     = (int*)(dinv + N);          // L
    int*   MTs    = MT + L;                    // L
    int*   bsums  = MTs + L;                   // ceil(L/1024)

    const int nb_scan = (L + SCAN_TILE - 1) / SCAN_TILE;

    hipLaunchKernelGGL(p1_hist, dim3(PBLK), dim3(256), 0, stream, dst, MT, E, NB, chunk);
    hipLaunchKernelGGL(scanA_kernel, dim3(nb_scan), dim3(256), 0, stream, MT, MTs, bsums, L);
    hipLaunchKernelGGL(scanB_kernel, dim3(1), dim3(256), 0, stream, bsums, nb_scan);
    hipLaunchKernelGGL(scanC_kernel, dim3((L + 255) / 256), dim3(256), 0, stream, MTs, bsums, L);
    hipLaunchKernelGGL(p2_part, dim3(PBLK), dim3(256), 0, stream, src, dst, ew, MTs, pp, pw, E, NB, chunk);
    hipLaunchKernelGGL(p3_bucket, dim3(NB), dim3(256), 0, stream, pp, pw, MTs, srcs, norms, rowptr, dinv, E, N, NB);
    hipLaunchKernelGGL(finalize_kernel, dim3((N + 3) / 4), dim3(256), 0, stream, rowptr, srcs, dinv, norms, N);

    // layer 1: xw = x@W1 -> bufA ; h = relu(agg(bufA)+b1) -> d_out
    hipLaunchKernelGGL(gemm128, dim3((N + 63) / 64), dim3(256), 0, stream, x, W1, bufA, N);
    hipLaunchKernelGGL(agg_kernel, dim3((N + 3) / 4), dim3(256), 0, stream, bufA, rowptr, srcs, norms, dinv, b1, out, N);

    // layer 2: hw = h@W2 -> bufA ; out = relu(agg(bufA)+b2) -> d_out
    hipLaunchKernelGGL(gemm128, dim3((N + 63) / 64), dim3(256), 0, stream, out, W2, bufA, N);
    hipLaunchKernelGGL(agg_kernel, dim3((N + 3) / 4), dim3(256), 0, stream, bufA, rowptr, srcs, norms, dinv, b2, out, N);
}

// Round 4
// 339.956 us; speedup vs baseline: 2.5814x; 1.3932x over previous
//
#include <hip/hip_runtime.h>
#include <hip/hip_bf16.h>

#define NPB 256        // nodes per bucket (dst >> 8)
#define PBLK 256       // partition blocks

// ---------------- phase 1: per-(block,bucket) histogram ----------------
__global__ __launch_bounds__(256) void p1_hist(const int* __restrict__ dst,
                                               int* __restrict__ MT, int E, int NB, int chunk) {
    __shared__ int h[512];
    int t = threadIdx.x, p = blockIdx.x;
    for (int i = t; i < NB; i += 256) h[i] = 0;
    __syncthreads();
    int beg = p * chunk, end = min(beg + chunk, E);
    for (int e = beg + t; e < end; e += 256) atomicAdd(&h[dst[e] >> 8], 1);
    __syncthreads();
    for (int b = t; b < NB; b += 256) MT[b * PBLK + p] = h[b];
}

// ---------------- device-wide exclusive scan (1024-elem tiles) ----------------
#define SCAN_TILE 1024

__global__ __launch_bounds__(256) void scanA_kernel(const int* __restrict__ in,
                                                    int* __restrict__ out,
                                                    int* __restrict__ blocksums, int n) {
    __shared__ int sums[256];
    int t = threadIdx.x;
    int base = blockIdx.x * SCAN_TILE + t * 4;
    int v0 = (base + 0 < n) ? in[base + 0] : 0;
    int v1 = (base + 1 < n) ? in[base + 1] : 0;
    int v2 = (base + 2 < n) ? in[base + 2] : 0;
    int v3 = (base + 3 < n) ? in[base + 3] : 0;
    sums[t] = v0 + v1 + v2 + v3;
    __syncthreads();
    for (int off = 1; off < 256; off <<= 1) {
        int add = (t >= off) ? sums[t - off] : 0;
        __syncthreads();
        sums[t] += add;
        __syncthreads();
    }
    int run = (t == 0) ? 0 : sums[t - 1];
    if (base + 0 < n) out[base + 0] = run; run += v0;
    if (base + 1 < n) out[base + 1] = run; run += v1;
    if (base + 2 < n) out[base + 2] = run; run += v2;
    if (base + 3 < n) out[base + 3] = run;
    if (t == 255) blocksums[blockIdx.x] = sums[255];
}

__global__ __launch_bounds__(256) void scanB_kernel(int* __restrict__ blocksums, int nb) {
    __shared__ int sums[256];
    int t = threadIdx.x;
    sums[t] = (t < nb) ? blocksums[t] : 0;
    __syncthreads();
    for (int off = 1; off < 256; off <<= 1) {
        int add = (t >= off) ? sums[t - off] : 0;
        __syncthreads();
        sums[t] += add;
        __syncthreads();
    }
    if (t < nb) blocksums[t] = (t == 0) ? 0 : sums[t - 1];
}

__global__ __launch_bounds__(256) void scanC_kernel(int* __restrict__ data,
                                                    const int* __restrict__ blocksums, int n) {
    int i = blockIdx.x * 256 + threadIdx.x;
    if (i < n) data[i] += blocksums[i / SCAN_TILE];
}

// ---------------- phase 2: partition edges into buckets (LDS cursors only) ----------------
__global__ __launch_bounds__(256) void p2_part(const int* __restrict__ src,
                                               const int* __restrict__ dst,
                                               const float* __restrict__ ew,
                                               const int* __restrict__ MTs,
                                               int* __restrict__ pp, float* __restrict__ pw,
                                               int E, int NB, int chunk) {
    __shared__ int cur[512];
    int t = threadIdx.x, p = blockIdx.x;
    for (int b = t; b < NB; b += 256) cur[b] = MTs[b * PBLK + p];
    __syncthreads();
    int beg = p * chunk, end = min(beg + chunk, E);
    for (int e = beg + t; e < end; e += 256) {
        int d = dst[e];
        int b = d >> 8;
        int pos = atomicAdd(&cur[b], 1);
        pp[pos] = src[e] | ((d & 255) << 20);   // src < 2^20, dlocal in [0,256)
        pw[pos] = ew[e];
    }
}

// ---------------- phase 3: per-bucket exact CSR + degree + dinv ----------------
// writes raw ew into norms slot (dinv factors are folded into GEMM epilogue / agg epilogue)
__global__ __launch_bounds__(256) void p3_bucket(const int* __restrict__ pp,
                                                 const float* __restrict__ pw,
                                                 const int* __restrict__ MTs,
                                                 int* __restrict__ srcs,
                                                 float* __restrict__ ews,
                                                 int* __restrict__ rowptr,
                                                 float* __restrict__ dinv,
                                                 int E, int N, int NB) {
    __shared__ int cnt[256];
    __shared__ float wd[256];
    __shared__ int ls[256];
    __shared__ int cur[256];
    int t = threadIdx.x, b = blockIdx.x;
    int beg = MTs[b * PBLK];
    int end = (b == NB - 1) ? E : MTs[(b + 1) * PBLK];
    cnt[t] = 0;
    wd[t] = 0.0f;
    __syncthreads();
    for (int e = beg + t; e < end; e += 256) {
        int v = pp[e];
        int dl = v >> 20;
        atomicAdd(&cnt[dl], 1);
        atomicAdd(&wd[dl], pw[e]);
    }
    __syncthreads();
    ls[t] = cnt[t];
    __syncthreads();
    for (int off = 1; off < 256; off <<= 1) {
        int add = (t >= off) ? ls[t - off] : 0;
        __syncthreads();
        ls[t] += add;
        __syncthreads();
    }
    int excl = (t == 0) ? 0 : ls[t - 1];
    int node = b * NPB + t;
    if (node < N) {
        rowptr[node] = beg + excl;
        dinv[node] = rsqrtf(1.0f + wd[t]);   // +1 = self-loop weight
    }
    cur[t] = beg + excl;
    if (b == NB - 1 && t == 0) rowptr[N] = E;
    __syncthreads();
    for (int e = beg + t; e < end; e += 256) {
        int v = pp[e];
        int dl = v >> 20;
        int pos = atomicAdd(&cur[dl], 1);
        srcs[pos] = v & 0xFFFFF;
        ews[pos] = pw[e];
    }
}

// ---------------- dense GEMM: Ybf16[r,:] = bf16(dinv[r] * (X[r,:] @ W)) ----------------
__global__ __launch_bounds__(256) void gemm128_bf16out(const float* __restrict__ X,
                                                       const float* __restrict__ W,
                                                       const float* __restrict__ dinv,
                                                       __hip_bfloat16* __restrict__ Y,
                                                       int nrows) {
    __shared__ float As[64 * 33];
    __shared__ float Ws[32 * 132];

    int t  = threadIdx.x;
    int ty = t >> 4;
    int tx = t & 15;
    int r0 = blockIdx.x * 64;

    float acc[4][8];
#pragma unroll
    for (int i = 0; i < 4; ++i)
#pragma unroll
        for (int j = 0; j < 8; ++j) acc[i][j] = 0.0f;

    for (int kb = 0; kb < 4; ++kb) {
        {
            int k = t & 31;
            int rbase = (t >> 5) * 8;
#pragma unroll
            for (int j = 0; j < 8; ++j) {
                int r = rbase + j;
                int gr = r0 + r;
                float v = 0.0f;
                if (gr < nrows) v = X[(size_t)gr * 128 + kb * 32 + k];
                As[r * 33 + k] = v;
            }
        }
        {
            int wr = t >> 3;
            int wc = (t & 7) * 16;
            const float4* Wg = (const float4*)(W + (size_t)(kb * 32 + wr) * 128 + wc);
            float4* Wl = (float4*)(Ws + wr * 132 + wc);
#pragma unroll
            for (int j = 0; j < 4; ++j) Wl[j] = Wg[j];
        }
        __syncthreads();

#pragma unroll 8
        for (int k = 0; k < 32; ++k) {
            float a[4];
#pragma unroll
            for (int i = 0; i < 4; ++i) a[i] = As[(ty * 4 + i) * 33 + k];
            float4 b0 = *(const float4*)(Ws + k * 132 + tx * 8);
            float4 b1 = *(const float4*)(Ws + k * 132 + tx * 8 + 4);
#pragma unroll
            for (int i = 0; i < 4; ++i) {
                acc[i][0] += a[i] * b0.x;
                acc[i][1] += a[i] * b0.y;
                acc[i][2] += a[i] * b0.z;
                acc[i][3] += a[i] * b0.w;
                acc[i][4] += a[i] * b1.x;
                acc[i][5] += a[i] * b1.y;
                acc[i][6] += a[i] * b1.z;
                acc[i][7] += a[i] * b1.w;
            }
        }
        __syncthreads();
    }

#pragma unroll
    for (int i = 0; i < 4; ++i) {
        int gr = r0 + ty * 4 + i;
        if (gr < nrows) {
            float s = dinv[gr];
            unsigned u[4];
#pragma unroll
            for (int j = 0; j < 4; ++j) {
                __hip_bfloat16 lo = __float2bfloat16(s * acc[i][2 * j]);
                __hip_bfloat16 hi = __float2bfloat16(s * acc[i][2 * j + 1]);
                u[j] = (unsigned)__bfloat16_as_ushort(lo) |
                       ((unsigned)__bfloat16_as_ushort(hi) << 16);
            }
            uint4 pk = {u[0], u[1], u[2], u[3]};
            *(uint4*)(Y + (size_t)gr * 128 + tx * 8) = pk;
        }
    }
}

// ---------------- aggregation over bf16 scaled features ----------------
// out[d] = relu( dinv[d] * ( sum_e ew[e]*Fs[src_e] + Fs[d] ) + bias ),  Fs = dinv.*XW (bf16)
// one wave per node, lane handles cols 2*lane, 2*lane+1 (one 4B load = 2 bf16)
__global__ __launch_bounds__(256) void agg_kernel(const __hip_bfloat16* __restrict__ F,
                                                  const int* __restrict__ rowptr,
                                                  const int* __restrict__ srcs,
                                                  const float* __restrict__ ews,
                                                  const float* __restrict__ dinv,
                                                  const float* __restrict__ bias,
                                                  float* __restrict__ out, int n) {
    const unsigned* Fu = (const unsigned*)F;   // one uint = 2 bf16 cols
    int wid  = (blockIdx.x * 256 + threadIdx.x) >> 6;
    int lane = threadIdx.x & 63;
    int node = __builtin_amdgcn_readfirstlane(wid);
    if (node >= n) return;

    int beg = rowptr[node];
    int end = rowptr[node + 1];
    float di = dinv[node];

    unsigned sv = Fu[(size_t)node * 64 + lane];
    float accx = __uint_as_float(sv << 16);
    float accy = __uint_as_float(sv & 0xFFFF0000u);

    int e = beg;
    for (; e + 4 <= end; e += 4) {
        int s0 = srcs[e + 0], s1 = srcs[e + 1], s2 = srcs[e + 2], s3 = srcs[e + 3];
        float w0 = ews[e + 0], w1 = ews[e + 1], w2 = ews[e + 2], w3 = ews[e + 3];
        unsigned v0 = Fu[(size_t)s0 * 64 + lane];
        unsigned v1 = Fu[(size_t)s1 * 64 + lane];
        unsigned v2 = Fu[(size_t)s2 * 64 + lane];
        unsigned v3 = Fu[(size_t)s3 * 64 + lane];
        accx += w0 * __uint_as_float(v0 << 16);
        accy += w0 * __uint_as_float(v0 & 0xFFFF0000u);
        accx += w1 * __uint_as_float(v1 << 16);
        accy += w1 * __uint_as_float(v1 & 0xFFFF0000u);
        accx += w2 * __uint_as_float(v2 << 16);
        accy += w2 * __uint_as_float(v2 & 0xFFFF0000u);
        accx += w3 * __uint_as_float(v3 << 16);
        accy += w3 * __uint_as_float(v3 & 0xFFFF0000u);
    }
    for (; e < end; ++e) {
        int s = srcs[e];
        float w = ews[e];
        unsigned v = Fu[(size_t)s * 64 + lane];
        accx += w * __uint_as_float(v << 16);
        accy += w * __uint_as_float(v & 0xFFFF0000u);
    }

    float2 bv = *(const float2*)(bias + 2 * lane);
    accx = fmaxf(di * accx + bv.x, 0.0f);
    accy = fmaxf(di * accy + bv.y, 0.0f);
    *(float2*)(out + (size_t)node * 128 + 2 * lane) = make_float2(accx, accy);
}

// ---------------- launcher ----------------

extern "C" void kernel_launch(void* const* d_in, const int* in_sizes, int n_in,
                              void* d_out, int out_size, void* d_ws, size_t ws_size,
                              hipStream_t stream) {
    const float* x  = (const float*)d_in[0];
    const int*   ei = (const int*)d_in[1];
    const float* ew = (const float*)d_in[2];
    const float* W1 = (const float*)d_in[3];
    const float* b1 = (const float*)d_in[4];
    const float* W2 = (const float*)d_in[5];
    const float* b2 = (const float*)d_in[6];
    float* out = (float*)d_out;

    const int N = in_sizes[0] / 128;
    const int E = in_sizes[2];
    const int* src = ei;
    const int* dst = ei + E;

    const int NB = (N + NPB - 1) / NPB;        // buckets (391 for N=100k)
    const int L  = NB * PBLK;                  // count-matrix length
    const int chunk = (E + PBLK - 1) / PBLK;

    // workspace layout. pp/pw alias the bf16 feature buffer (dead before GEMM writes it).
    __hip_bfloat16* bufB = (__hip_bfloat16*)d_ws;      // N*128 bf16 (25.6 MB)
    int*   pp     = (int*)d_ws;                        // E ints   (alias)
    float* pw     = (float*)(pp + E);                  // E floats (alias; pp+pw = 12.8 MB < 25.6 MB)
    int*   srcs   = (int*)((char*)d_ws + (size_t)N * 128 * sizeof(__hip_bfloat16));  // E
    float* ews    = (float*)(srcs + E);        // E
    int*   rowptr = (int*)(ews + E);           // N+1
    float* dinv   = (float*)(rowptr + N + 1);  // N
    int*   MT     = (int*)(dinv + N);          // L
    int*   MTs    = MT + L;                    // L
    int*   bsums  = MTs + L;                   // ceil(L/1024)

    const int nb_scan = (L + SCAN_TILE - 1) / SCAN_TILE;

    hipLaunchKernelGGL(p1_hist, dim3(PBLK), dim3(256), 0, stream, dst, MT, E, NB, chunk);
    hipLaunchKernelGGL(scanA_kernel, dim3(nb_scan), dim3(256), 0, stream, MT, MTs, bsums, L);
    hipLaunchKernelGGL(scanB_kernel, dim3(1), dim3(256), 0, stream, bsums, nb_scan);
    hipLaunchKernelGGL(scanC_kernel, dim3((L + 255) / 256), dim3(256), 0, stream, MTs, bsums, L);
    hipLaunchKernelGGL(p2_part, dim3(PBLK), dim3(256), 0, stream, src, dst, ew, MTs, pp, pw, E, NB, chunk);
    hipLaunchKernelGGL(p3_bucket, dim3(NB), dim3(256), 0, stream, pp, pw, MTs, srcs, ews, rowptr, dinv, E, N, NB);

    // layer 1: Fs = bf16(dinv .* (x@W1)) -> bufB ; h = relu(dinv.*(agg(bufB))+b1) -> d_out
    hipLaunchKernelGGL(gemm128_bf16out, dim3((N + 63) / 64), dim3(256), 0, stream, x, W1, dinv, bufB, N);
    hipLaunchKernelGGL(agg_kernel, dim3((N + 3) / 4), dim3(256), 0, stream, bufB, rowptr, srcs, ews, dinv, b1, out, N);

    // layer 2: Fs = bf16(dinv .* (h@W2)) -> bufB ; out = relu(dinv.*(agg(bufB))+b2) -> d_out
    hipLaunchKernelGGL(gemm128_bf16out, dim3((N + 63) / 64), dim3(256), 0, stream, out, W2, dinv, bufB, N);
    hipLaunchKernelGGL(agg_kernel, dim3((N + 3) / 4), dim3(256), 0, stream, bufB, rowptr, srcs, ews, dinv, b2, out, N);
}

// Round 5
// 259.967 us; speedup vs baseline: 3.3757x; 1.3077x over previous
//
#include <hip/hip_runtime.h>
#include <hip/hip_bf16.h>

typedef __attribute__((ext_vector_type(8))) short short8;
typedef __attribute__((ext_vector_type(4))) float f32x4;

#define NPB 256        // nodes per bucket (dst >> 8)
#define PBLK 256       // partition blocks
#define SCAN_TILE 1024
#define GPANEL 32      // GEMM A-panel rows

// ---------------- phase 1: per-(block,bucket) histogram ----------------
__global__ __launch_bounds__(256) void p1_hist(const int* __restrict__ dst,
                                               int* __restrict__ MT, int E, int NB, int chunk) {
    __shared__ int h[512];
    int t = threadIdx.x, p = blockIdx.x;
    for (int i = t; i < NB; i += 256) h[i] = 0;
    __syncthreads();
    int beg = p * chunk, end = min(beg + chunk, E);
    for (int e = beg + t; e < end; e += 256) atomicAdd(&h[dst[e] >> 8], 1);
    __syncthreads();
    for (int b = t; b < NB; b += 256) MT[b * PBLK + p] = h[b];
}

// ---------------- device-wide exclusive scan (1024-elem tiles) ----------------
__global__ __launch_bounds__(256) void scanA_kernel(const int* __restrict__ in,
                                                    int* __restrict__ out,
                                                    int* __restrict__ blocksums, int n) {
    __shared__ int sums[256];
    int t = threadIdx.x;
    int base = blockIdx.x * SCAN_TILE + t * 4;
    int v0 = (base + 0 < n) ? in[base + 0] : 0;
    int v1 = (base + 1 < n) ? in[base + 1] : 0;
    int v2 = (base + 2 < n) ? in[base + 2] : 0;
    int v3 = (base + 3 < n) ? in[base + 3] : 0;
    sums[t] = v0 + v1 + v2 + v3;
    __syncthreads();
    for (int off = 1; off < 256; off <<= 1) {
        int add = (t >= off) ? sums[t - off] : 0;
        __syncthreads();
        sums[t] += add;
        __syncthreads();
    }
    int run = (t == 0) ? 0 : sums[t - 1];
    if (base + 0 < n) out[base + 0] = run; run += v0;
    if (base + 1 < n) out[base + 1] = run; run += v1;
    if (base + 2 < n) out[base + 2] = run; run += v2;
    if (base + 3 < n) out[base + 3] = run;
    if (t == 255) blocksums[blockIdx.x] = sums[255];
}

__global__ __launch_bounds__(256) void scanB_kernel(int* __restrict__ blocksums, int nb) {
    __shared__ int sums[256];
    int t = threadIdx.x;
    sums[t] = (t < nb) ? blocksums[t] : 0;
    __syncthreads();
    for (int off = 1; off < 256; off <<= 1) {
        int add = (t >= off) ? sums[t - off] : 0;
        __syncthreads();
        sums[t] += add;
        __syncthreads();
    }
    if (t < nb) blocksums[t] = (t == 0) ? 0 : sums[t - 1];
}

__global__ __launch_bounds__(256) void scanC_kernel(int* __restrict__ data,
                                                    const int* __restrict__ blocksums, int n) {
    int i = blockIdx.x * 256 + threadIdx.x;
    if (i < n) data[i] += blocksums[i / SCAN_TILE];
}

// ---------------- phase 2: partition edges into buckets (LDS cursors only) ----------------
__global__ __launch_bounds__(256) void p2_part(const int* __restrict__ src,
                                               const int* __restrict__ dst,
                                               const float* __restrict__ ew,
                                               const int* __restrict__ MTs,
                                               int* __restrict__ pp, float* __restrict__ pw,
                                               int E, int NB, int chunk) {
    __shared__ int cur[512];
    int t = threadIdx.x, p = blockIdx.x;
    for (int b = t; b < NB; b += 256) cur[b] = MTs[b * PBLK + p];
    __syncthreads();
    int beg = p * chunk, end = min(beg + chunk, E);
    for (int e = beg + t; e < end; e += 256) {
        int d = dst[e];
        int b = d >> 8;
        int pos = atomicAdd(&cur[b], 1);
        pp[pos] = src[e] | ((d & 255) << 20);   // src < 2^20, dlocal in [0,256)
        pw[pos] = ew[e];
    }
}

// ---------------- phase 3: per-bucket exact CSR + degree + dinv ----------------
__global__ __launch_bounds__(256) void p3_bucket(const int* __restrict__ pp,
                                                 const float* __restrict__ pw,
                                                 const int* __restrict__ MTs,
                                                 int* __restrict__ srcs,
                                                 float* __restrict__ ews,
                                                 int* __restrict__ rowptr,
                                                 float* __restrict__ dinv,
                                                 int E, int N, int NB) {
    __shared__ int cnt[256];
    __shared__ float wd[256];
    __shared__ int ls[256];
    __shared__ int cur[256];
    int t = threadIdx.x, b = blockIdx.x;
    int beg = MTs[b * PBLK];
    int end = (b == NB - 1) ? E : MTs[(b + 1) * PBLK];
    cnt[t] = 0;
    wd[t] = 0.0f;
    __syncthreads();
    for (int e = beg + t; e < end; e += 256) {
        int v = pp[e];
        int dl = v >> 20;
        atomicAdd(&cnt[dl], 1);
        atomicAdd(&wd[dl], pw[e]);
    }
    __syncthreads();
    ls[t] = cnt[t];
    __syncthreads();
    for (int off = 1; off < 256; off <<= 1) {
        int add = (t >= off) ? ls[t - off] : 0;
        __syncthreads();
        ls[t] += add;
        __syncthreads();
    }
    int excl = (t == 0) ? 0 : ls[t - 1];
    int node = b * NPB + t;
    if (node < N) {
        rowptr[node] = beg + excl;
        dinv[node] = rsqrtf(1.0f + wd[t]);   // +1 = self-loop weight
    }
    cur[t] = beg + excl;
    if (b == NB - 1 && t == 0) rowptr[N] = E;
    __syncthreads();
    for (int e = beg + t; e < end; e += 256) {
        int v = pp[e];
        int dl = v >> 20;
        int pos = atomicAdd(&cur[dl], 1);
        srcs[pos] = v & 0xFFFFF;
        ews[pos] = pw[e];
    }
}

// ---------------- MFMA GEMM: Fs = bf16( dinv .* (A @ W) ) ----------------
// Split precision: A ~= Ahi+Alo, W ~= Whi+Wlo (bf16); P = Ahi*Whi + Alo*Whi + Ahi*Wlo
// Block: 256 thr (4 waves). W (128x128) staged once per block (transposed + split,
// XOR-swizzled). A panels of 32 rows grid-strided. LDS = 80 KB -> 2 blocks/CU.
// 16x16x32 bf16 MFMA; A: row=lane&15,k=8*(lane>>4); C/D: col=lane&15,row=(lane>>4)*4+reg.
__global__ __launch_bounds__(256) void gemm_mfma(const float* __restrict__ A,
                                                 const float* __restrict__ W,
                                                 const float* __restrict__ dinv,
                                                 __hip_bfloat16* __restrict__ Fs,
                                                 int nrows) {
    __shared__ short sWhi[128 * 128];
    __shared__ short sWlo[128 * 128];
    __shared__ short sAhi[GPANEL * 128];
    __shared__ short sAlo[GPANEL * 128];

    const int t = threadIdx.x;

    // ---- stage whole W: transposed [col][k], hi/lo split, swizzled ----
    for (int i = t; i < 128 * 128; i += 256) {
        int k = i >> 7, c = i & 127;
        float w = W[i];
        __hip_bfloat16 h = __float2bfloat16(w);
        float hf = __bfloat162float(h);
        __hip_bfloat16 l = __float2bfloat16(w - hf);
        int idx = (c * 128 + k) ^ ((c & 7) << 3);
        sWhi[idx] = (short)__bfloat16_as_ushort(h);
        sWlo[idx] = (short)__bfloat16_as_ushort(l);
    }

    const int lane = t & 63;
    const int wave = t >> 6;
    const int wm = wave & 1;       // row half of panel (16 rows)
    const int wn = wave >> 1;      // col half (64 cols)
    const int fr = lane & 15;      // frag row/col index
    const int kq = lane >> 4;      // 0..3 -> k sub-offset 8*kq

    // A staging coords: thread covers row sr, k-range [sk, sk+16)
    const int sr = t >> 3;
    const int sk = (t & 7) * 16;

    const int npan = (nrows + GPANEL - 1) / GPANEL;

    for (int p = blockIdx.x; p < npan; p += gridDim.x) {
        __syncthreads();
        // ---- stage A panel (fp32 -> hi/lo bf16, swizzled) ----
        {
            float4 v[4];
            int gr = p * GPANEL + sr;
            if (gr < nrows) {
                const float4* Ag = (const float4*)(A + (size_t)gr * 128 + sk);
                v[0] = Ag[0]; v[1] = Ag[1]; v[2] = Ag[2]; v[3] = Ag[3];
            } else {
                float4 z = {0.f, 0.f, 0.f, 0.f};
                v[0] = z; v[1] = z; v[2] = z; v[3] = z;
            }
            short hi[16], lo[16];
            const float* vf = (const float*)v;
#pragma unroll
            for (int j = 0; j < 16; ++j) {
                __hip_bfloat16 h = __float2bfloat16(vf[j]);
                hi[j] = (short)__bfloat16_as_ushort(h);
                lo[j] = (short)__bfloat16_as_ushort(__float2bfloat16(vf[j] - __bfloat162float(h)));
            }
            int base0 = (sr * 128 + sk) ^ ((sr & 7) << 3);
            int base1 = (sr * 128 + sk + 8) ^ ((sr & 7) << 3);
            *(short8*)&sAhi[base0] = *(short8*)&hi[0];
            *(short8*)&sAhi[base1] = *(short8*)&hi[8];
            *(short8*)&sAlo[base0] = *(short8*)&lo[0];
            *(short8*)&sAlo[base1] = *(short8*)&lo[8];
        }
        __syncthreads();

        // ---- compute: wave tile = 16 rows x 64 cols ----
        f32x4 acc[4];
#pragma unroll
        for (int fc = 0; fc < 4; ++fc) acc[fc] = (f32x4){0.f, 0.f, 0.f, 0.f};

        const int arow = wm * 16 + fr;
#pragma unroll
        for (int ks = 0; ks < 4; ++ks) {
            int ak = ks * 32 + 8 * kq;
            int aidx = (arow * 128 + ak) ^ ((arow & 7) << 3);
            short8 ahi = *(short8*)&sAhi[aidx];
            short8 alo = *(short8*)&sAlo[aidx];
#pragma unroll
            for (int fc = 0; fc < 4; ++fc) {
                int c = wn * 64 + fc * 16 + fr;
                int bidx = (c * 128 + ak) ^ ((c & 7) << 3);
                short8 bhi = *(short8*)&sWhi[bidx];
                short8 blo = *(short8*)&sWlo[bidx];
                acc[fc] = __builtin_amdgcn_mfma_f32_16x16x32_bf16(ahi, bhi, acc[fc], 0, 0, 0);
                acc[fc] = __builtin_amdgcn_mfma_f32_16x16x32_bf16(alo, bhi, acc[fc], 0, 0, 0);
                acc[fc] = __builtin_amdgcn_mfma_f32_16x16x32_bf16(ahi, blo, acc[fc], 0, 0, 0);
            }
        }

        // ---- epilogue: scale by dinv[row], convert bf16, store ----
        int rb = p * GPANEL + wm * 16 + kq * 4;
#pragma unroll
        for (int r = 0; r < 4; ++r) {
            int grow = rb + r;
            if (grow < nrows) {
                float s = dinv[grow];
#pragma unroll
                for (int fc = 0; fc < 4; ++fc) {
                    int col = wn * 64 + fc * 16 + fr;
                    Fs[(size_t)grow * 128 + col] = __float2bfloat16(s * acc[fc][r]);
                }
            }
        }
    }
}

// ---------------- aggregation over bf16 scaled features ----------------
// out[d] = relu( dinv[d] * ( sum_e ew[e]*Fs[src_e] + Fs[d] ) + bias )
__global__ __launch_bounds__(256) void agg_kernel(const __hip_bfloat16* __restrict__ F,
                                                  const int* __restrict__ rowptr,
                                                  const int* __restrict__ srcs,
                                                  const float* __restrict__ ews,
                                                  const float* __restrict__ dinv,
                                                  const float* __restrict__ bias,
                                                  float* __restrict__ out, int n) {
    const unsigned* Fu = (const unsigned*)F;   // one uint = 2 bf16 cols
    int wid  = (blockIdx.x * 256 + threadIdx.x) >> 6;
    int lane = threadIdx.x & 63;
    int node = __builtin_amdgcn_readfirstlane(wid);
    if (node >= n) return;

    int beg = rowptr[node];
    int end = rowptr[node + 1];
    float di = dinv[node];

    unsigned sv = Fu[(size_t)node * 64 + lane];
    float accx = __uint_as_float(sv << 16);
    float accy = __uint_as_float(sv & 0xFFFF0000u);

    int e = beg;
    for (; e + 4 <= end; e += 4) {
        int s0 = srcs[e + 0], s1 = srcs[e + 1], s2 = srcs[e + 2], s3 = srcs[e + 3];
        float w0 = ews[e + 0], w1 = ews[e + 1], w2 = ews[e + 2], w3 = ews[e + 3];
        unsigned v0 = Fu[(size_t)s0 * 64 + lane];
        unsigned v1 = Fu[(size_t)s1 * 64 + lane];
        unsigned v2 = Fu[(size_t)s2 * 64 + lane];
        unsigned v3 = Fu[(size_t)s3 * 64 + lane];
        accx += w0 * __uint_as_float(v0 << 16);
        accy += w0 * __uint_as_float(v0 & 0xFFFF0000u);
        accx += w1 * __uint_as_float(v1 << 16);
        accy += w1 * __uint_as_float(v1 & 0xFFFF0000u);
        accx += w2 * __uint_as_float(v2 << 16);
        accy += w2 * __uint_as_float(v2 & 0xFFFF0000u);
        accx += w3 * __uint_as_float(v3 << 16);
        accy += w3 * __uint_as_float(v3 & 0xFFFF0000u);
    }
    for (; e < end; ++e) {
        int s = srcs[e];
        float w = ews[e];
        unsigned v = Fu[(size_t)s * 64 + lane];
        accx += w * __uint_as_float(v << 16);
        accy += w * __uint_as_float(v & 0xFFFF0000u);
    }

    float2 bv = *(const float2*)(bias + 2 * lane);
    accx = fmaxf(di * accx + bv.x, 0.0f);
    accy = fmaxf(di * accy + bv.y, 0.0f);
    *(float2*)(out + (size_t)node * 128 + 2 * lane) = make_float2(accx, accy);
}

// ---------------- launcher ----------------

extern "C" void kernel_launch(void* const* d_in, const int* in_sizes, int n_in,
                              void* d_out, int out_size, void* d_ws, size_t ws_size,
                              hipStream_t stream) {
    const float* x  = (const float*)d_in[0];
    const int*   ei = (const int*)d_in[1];
    const float* ew = (const float*)d_in[2];
    const float* W1 = (const float*)d_in[3];
    const float* b1 = (const float*)d_in[4];
    const float* W2 = (const float*)d_in[5];
    const float* b2 = (const float*)d_in[6];
    float* out = (float*)d_out;

    const int N = in_sizes[0] / 128;
    const int E = in_sizes[2];
    const int* src = ei;
    const int* dst = ei + E;

    const int NB = (N + NPB - 1) / NPB;        // buckets (391 for N=100k)
    const int L  = NB * PBLK;                  // count-matrix length
    const int chunk = (E + PBLK - 1) / PBLK;

    // workspace layout. pp/pw alias the bf16 feature buffer (dead before GEMM writes it).
    __hip_bfloat16* bufB = (__hip_bfloat16*)d_ws;      // N*128 bf16 (25.6 MB)
    int*   pp     = (int*)d_ws;                        // E ints   (alias)
    float* pw     = (float*)(pp + E);                  // E floats (alias)
    int*   srcs   = (int*)((char*)d_ws + (size_t)N * 128 * sizeof(__hip_bfloat16));  // E
    float* ews    = (float*)(srcs + E);        // E
    int*   rowptr = (int*)(ews + E);           // N+1
    float* dinv   = (float*)(rowptr + N + 1);  // N
    int*   MT     = (int*)(dinv + N);          // L
    int*   MTs    = MT + L;                    // L
    int*   bsums  = MTs + L;                   // ceil(L/1024)

    const int nb_scan = (L + SCAN_TILE - 1) / SCAN_TILE;
    const int npan = (N + GPANEL - 1) / GPANEL;
    const int gblocks = npan < 512 ? npan : 512;

    hipLaunchKernelGGL(p1_hist, dim3(PBLK), dim3(256), 0, stream, dst, MT, E, NB, chunk);
    hipLaunchKernelGGL(scanA_kernel, dim3(nb_scan), dim3(256), 0, stream, MT, MTs, bsums, L);
    hipLaunchKernelGGL(scanB_kernel, dim3(1), dim3(256), 0, stream, bsums, nb_scan);
    hipLaunchKernelGGL(scanC_kernel, dim3((L + 255) / 256), dim3(256), 0, stream, MTs, bsums, L);
    hipLaunchKernelGGL(p2_part, dim3(PBLK), dim3(256), 0, stream, src, dst, ew, MTs, pp, pw, E, NB, chunk);
    hipLaunchKernelGGL(p3_bucket, dim3(NB), dim3(256), 0, stream, pp, pw, MTs, srcs, ews, rowptr, dinv, E, N, NB);

    // layer 1: Fs = bf16(dinv .* (x@W1)) -> bufB ; h = relu(dinv.*(agg(bufB))+b1) -> d_out
    hipLaunchKernelGGL(gemm_mfma, dim3(gblocks), dim3(256), 0, stream, x, W1, dinv, bufB, N);
    hipLaunchKernelGGL(agg_kernel, dim3((N + 3) / 4), dim3(256), 0, stream, bufB, rowptr, srcs, ews, dinv, b1, out, N);

    // layer 2: Fs = bf16(dinv .* (h@W2)) -> bufB ; out = relu(dinv.*(agg(bufB))+b2) -> d_out
    hipLaunchKernelGGL(gemm_mfma, dim3(gblocks), dim3(256), 0, stream, out, W2, dinv, bufB, N);
    hipLaunchKernelGGL(agg_kernel, dim3((N + 3) / 4), dim3(256), 0, stream, bufB, rowptr, srcs, ews, dinv, b2, out, N);
}